// Round 1
// baseline (524.750 us; speedup 1.0000x reference)
//
#include <hip/hip_runtime.h>
#include <cstddef>

namespace {

constexpr int B_ = 4, L_ = 1024, H_ = 8;
constexpr int ROWS = 16;     // query rows per block
constexpr int PAD  = 68;     // padded LDS row stride (floats)
constexpr int NCHMAX = 16;   // 1024 / 64

__device__ inline float wmax(float v) {
#pragma unroll
  for (int off = 32; off; off >>= 1) v = fmaxf(v, __shfl_xor(v, off));
  return v;
}
__device__ inline float wsum(float v) {
#pragma unroll
  for (int off = 32; off; off >>= 1) v += __shfl_xor(v, off);
  return v;
}

__global__ __launch_bounds__(256) void fused_attn(
    const float* __restrict__ Qg, const float* __restrict__ Kg,
    const float* __restrict__ Vg, const float* __restrict__ Sg,
    const float* __restrict__ sacg, const int* __restrict__ tg,
    float* __restrict__ outV, float* __restrict__ outS,
    float* __restrict__ outP, float* __restrict__ outT)
{
  __shared__ __align__(16) float Qlds[ROWS * PAD];
  __shared__ __align__(16) float KVlds[64 * PAD];
  __shared__ __align__(16) float Plds[ROWS * PAD];

  const int tid = threadIdx.x;
  const int wv  = tid >> 6;
  const int ln  = tid & 63;
  const int ltile = blockIdx.x & 63;
  const int bh    = blockIdx.x >> 6;
  const int b = bh >> 3;
  const int h = bh & 7;
  const int l0 = ltile * ROWS;
  const int nch = (l0 + ROWS + 63) >> 6;  // chunks of 64 covering causal extent
  const int lw = l0 + wv * 4;             // this wave's first row

  // ---- stage Q tile (16 rows x 64) ----
  {
    const int r = tid >> 4, part = tid & 15;
    const float4 q4 = *reinterpret_cast<const float4*>(
        Qg + ((size_t)((b * L_ + l0 + r) * H_ + h) << 6) + part * 4);
    *reinterpret_cast<float4*>(Qlds + r * PAD + part * 4) = q4;
  }

  float sc[4][NCHMAX];  // scores -> exp -> P (statically indexed, fully unrolled)

  // ---- QK^T ----
#pragma unroll
  for (int c = 0; c < NCHMAX; ++c) {
    if (c < nch) {
      __syncthreads();
      {
        const int part = tid & 15, jb = tid >> 4;
#pragma unroll
        for (int jj = 0; jj < 4; ++jj) {
          const int j = jb + jj * 16;
          const float4 kv = *reinterpret_cast<const float4*>(
              Kg + ((size_t)((b * L_ + c * 64 + j) * H_ + h) << 6) + part * 4);
          *reinterpret_cast<float4*>(KVlds + j * PAD + part * 4) = kv;
        }
      }
      __syncthreads();
      float a0 = 0.f, a1 = 0.f, a2 = 0.f, a3 = 0.f;
#pragma unroll
      for (int u = 0; u < 16; ++u) {
        const float4 kv = *reinterpret_cast<const float4*>(KVlds + ln * PAD + u * 4);
        const float4 q0 = *reinterpret_cast<const float4*>(Qlds + (wv * 4 + 0) * PAD + u * 4);
        const float4 q1 = *reinterpret_cast<const float4*>(Qlds + (wv * 4 + 1) * PAD + u * 4);
        const float4 q2 = *reinterpret_cast<const float4*>(Qlds + (wv * 4 + 2) * PAD + u * 4);
        const float4 q3 = *reinterpret_cast<const float4*>(Qlds + (wv * 4 + 3) * PAD + u * 4);
        a0 += kv.x * q0.x + kv.y * q0.y + kv.z * q0.z + kv.w * q0.w;
        a1 += kv.x * q1.x + kv.y * q1.y + kv.z * q1.z + kv.w * q1.w;
        a2 += kv.x * q2.x + kv.y * q2.y + kv.z * q2.z + kv.w * q2.w;
        a3 += kv.x * q3.x + kv.y * q3.y + kv.z * q3.z + kv.w * q3.w;
      }
      const int s = c * 64 + ln;
      sc[0][c] = (s <= lw + 0) ? a0 * 0.125f : -1e30f;
      sc[1][c] = (s <= lw + 1) ? a1 * 0.125f : -1e30f;
      sc[2][c] = (s <= lw + 2) ? a2 * 0.125f : -1e30f;
      sc[3][c] = (s <= lw + 3) ? a3 * 0.125f : -1e30f;
    }
  }

  // ---- softmax over registers (row spread across 64 lanes x nch chunks) ----
#pragma unroll
  for (int rr = 0; rr < 4; ++rr) {
    float m = -1e30f;
#pragma unroll
    for (int c = 0; c < NCHMAX; ++c) if (c < nch) m = fmaxf(m, sc[rr][c]);
    m = wmax(m);
    float s = 0.f;
#pragma unroll
    for (int c = 0; c < NCHMAX; ++c) if (c < nch) {
      const float e = __expf(sc[rr][c] - m);
      sc[rr][c] = e;
      s += e;
    }
    s = wsum(s);
    const float inv = 1.f / s;
#pragma unroll
    for (int c = 0; c < NCHMAX; ++c) if (c < nch) sc[rr][c] *= inv;
  }

  // ---- PV + series writes ----
  float acc0 = 0.f, acc1 = 0.f, acc2 = 0.f, acc3 = 0.f;
  const size_t serBase = ((size_t)(b * H_ + h) << 10);
#pragma unroll
  for (int c = 0; c < NCHMAX; ++c) {
    if (c < nch) {
      __syncthreads();
      {
        const int part = tid & 15, jb = tid >> 4;
#pragma unroll
        for (int jj = 0; jj < 4; ++jj) {
          const int j = jb + jj * 16;
          const float4 vv = *reinterpret_cast<const float4*>(
              Vg + ((size_t)((b * L_ + c * 64 + j) * H_ + h) << 6) + part * 4);
          *reinterpret_cast<float4*>(KVlds + j * PAD + part * 4) = vv;
        }
      }
      Plds[(wv * 4 + 0) * PAD + ln] = sc[0][c];
      Plds[(wv * 4 + 1) * PAD + ln] = sc[1][c];
      Plds[(wv * 4 + 2) * PAD + ln] = sc[2][c];
      Plds[(wv * 4 + 3) * PAD + ln] = sc[3][c];
      __syncthreads();
      {
        const int r = tid >> 4, part = tid & 15;
        const float4 pv = *reinterpret_cast<const float4*>(Plds + r * PAD + part * 4);
        *reinterpret_cast<float4*>(outS + ((serBase + l0 + r) << 10) + c * 64 + part * 4) = pv;
      }
#pragma unroll
      for (int u = 0; u < 16; ++u) {
        const float v0 = KVlds[(u * 4 + 0) * PAD + ln];
        const float v1 = KVlds[(u * 4 + 1) * PAD + ln];
        const float v2 = KVlds[(u * 4 + 2) * PAD + ln];
        const float v3 = KVlds[(u * 4 + 3) * PAD + ln];
        const float4 p0 = *reinterpret_cast<const float4*>(Plds + (wv * 4 + 0) * PAD + u * 4);
        const float4 p1 = *reinterpret_cast<const float4*>(Plds + (wv * 4 + 1) * PAD + u * 4);
        const float4 p2 = *reinterpret_cast<const float4*>(Plds + (wv * 4 + 2) * PAD + u * 4);
        const float4 p3 = *reinterpret_cast<const float4*>(Plds + (wv * 4 + 3) * PAD + u * 4);
        acc0 += p0.x * v0 + p0.y * v1 + p0.z * v2 + p0.w * v3;
        acc1 += p1.x * v0 + p1.y * v1 + p1.z * v2 + p1.w * v3;
        acc2 += p2.x * v0 + p2.y * v1 + p2.z * v2 + p2.w * v3;
        acc3 += p3.x * v0 + p3.y * v1 + p3.z * v2 + p3.w * v3;
      }
    } else {
      const int r = tid >> 4, part = tid & 15;
      *reinterpret_cast<float4*>(outS + ((serBase + l0 + r) << 10) + c * 64 + part * 4) =
          make_float4(0.f, 0.f, 0.f, 0.f);
    }
  }

  outV[((size_t)((b * L_ + lw + 0) * H_ + h) << 6) + ln] = acc0;
  outV[((size_t)((b * L_ + lw + 1) * H_ + h) << 6) + ln] = acc1;
  outV[((size_t)((b * L_ + lw + 2) * H_ + h) << 6) + ln] = acc2;
  outV[((size_t)((b * L_ + lw + 3) * H_ + h) << 6) + ln] = acc3;

  // ---- prior + sigma_t (per-row constant sigma) ----
  const float sacb = sacg[tg[b]];
#pragma unroll
  for (int rr = 0; rr < 4; ++rr) {
    const int l = lw + rr;
    const float sgv = Sg[(size_t)(b * L_ + l) * H_ + h];
    const float sig = 1.f / (1.f + __expf(-5.f * sgv)) + 1e-5f;
    const float st  = sacb * (__expf(sig * 1.0986122886681098f) - 1.f);  // sac * (3^sig - 1)
    const float coef = 0.3989422804014327f / st;
    const float qc   = -0.5f / (st * st);
    float* prow = outP + ((serBase + l) << 10);
    float* trow = outT + ((serBase + l) << 10);
    const float4 stv = make_float4(st, st, st, st);
#pragma unroll
    for (int g = 0; g < 4; ++g) {
      const int s0 = g * 256 + ln * 4;
      const float d0 = (float)(l - s0);
      const float d1 = d0 - 1.f, d2 = d0 - 2.f, d3 = d0 - 3.f;
      float4 pr;
      pr.x = coef * __expf(qc * d0 * d0);
      pr.y = coef * __expf(qc * d1 * d1);
      pr.z = coef * __expf(qc * d2 * d2);
      pr.w = coef * __expf(qc * d3 * d3);
      *reinterpret_cast<float4*>(prow + s0) = pr;
      *reinterpret_cast<float4*>(trow + s0) = stv;
    }
  }
}

}  // namespace

extern "C" void kernel_launch(void* const* d_in, const int* in_sizes, int n_in,
                              void* d_out, int out_size, void* d_ws, size_t ws_size,
                              hipStream_t stream) {
  const float* Qg   = (const float*)d_in[0];
  const float* Kg   = (const float*)d_in[1];
  const float* Vg   = (const float*)d_in[2];
  const float* Sg   = (const float*)d_in[3];
  const float* sacg = (const float*)d_in[4];
  const int*   tg   = (const int*)d_in[5];

  float* out  = (float*)d_out;
  float* outV = out;                                  // 4*1024*8*64    = 2097152
  float* outS = out + (size_t)2097152;                // 4*8*1024*1024 = 33554432
  float* outP = out + (size_t)35651584;
  float* outT = out + (size_t)69206016;

  const int blocks = B_ * H_ * (L_ / ROWS);  // 4*8*64 = 2048
  hipLaunchKernelGGL(fused_attn, dim3(blocks), dim3(256), 0, stream,
                     Qg, Kg, Vg, Sg, sacg, tg, outV, outS, outP, outT);
}

// Round 2
// 145.381 us; speedup vs baseline: 3.6095x; 3.6095x over previous
//
#include <hip/hip_runtime.h>
#include <hip/hip_bf16.h>
#include <cstddef>
#include <cstdint>

namespace {

using f32x4  = __attribute__((ext_vector_type(4))) float;
using bf16x8 = __attribute__((ext_vector_type(8))) short;
using u16x2  = __attribute__((ext_vector_type(2))) unsigned short;
using u16x4  = __attribute__((ext_vector_type(4))) unsigned short;

constexpr int ATT_BLOCKS   = 1024;   // 32 qtiles x 32 (b,h)
constexpr int PRIOR_BLOCKS = 16384;  // 2 rows each -> 32768 rows

__device__ inline unsigned short f2bf(float x) {
  __hip_bfloat16 hv = __float2bfloat16(x);
  return *reinterpret_cast<unsigned short*>(&hv);
}

__device__ inline bf16x8 pack_bf8(f32x4 a, f32x4 b) {
  bf16x8 r;
  r[0] = (short)f2bf(a[0]); r[1] = (short)f2bf(a[1]);
  r[2] = (short)f2bf(a[2]); r[3] = (short)f2bf(a[3]);
  r[4] = (short)f2bf(b[0]); r[5] = (short)f2bf(b[1]);
  r[6] = (short)f2bf(b[2]); r[7] = (short)f2bf(b[3]);
  return r;
}

__global__ __launch_bounds__(128) void fused_all(
    const float* __restrict__ Qg, const float* __restrict__ Kg,
    const float* __restrict__ Vg, const float* __restrict__ Sg,
    const float* __restrict__ sacg, const int* __restrict__ tg,
    float* __restrict__ outV, float* __restrict__ outS,
    float* __restrict__ outP, float* __restrict__ outT)
{
  __shared__ unsigned short Vt[64 * 72];       // [d][s], stride 72 (144B rows, 16B aligned)
  __shared__ unsigned short Pl[2 * 16 * 72];   // per-wave [q][s], stride 72

  const int tid = threadIdx.x;

  if (blockIdx.x >= ATT_BLOCKS) {
    // ---------------- prior + sigma_t (pure streaming) ----------------
    const int pb = blockIdx.x - ATT_BLOCKS;
    const int r0 = pb * 2 + (tid >> 6);        // global row in [B][H][L]
    const int ln = tid & 63;
    const int b  = r0 >> 13;
    const int hh = (r0 >> 10) & 7;
    const int l  = r0 & 1023;
    const float sgv = Sg[(size_t)(b * 1024 + l) * 8 + hh];
    const float sac = sacg[tg[b]];
    const float sig = 1.f / (1.f + __expf(-5.f * sgv)) + 1e-5f;
    const float st  = sac * expm1f(sig * 1.0986122886681098f);  // sac*(3^sig-1)
    const float coef = 0.3989422804014327f / st;
    const float qc   = -0.5f / (st * st);
    float* pp = outP + ((size_t)r0 << 10);
    float* tp = outT + ((size_t)r0 << 10);
    const f32x4 stv = {st, st, st, st};
#pragma unroll
    for (int j = 0; j < 4; ++j) {
      const int c0 = j * 256 + ln * 4;         // per-instr contiguous 1KB across wave
      const float d0 = (float)(l - c0);
      const float d1 = d0 - 1.f, d2 = d0 - 2.f, d3 = d0 - 3.f;
      f32x4 pr;
      pr[0] = coef * __expf(qc * d0 * d0);
      pr[1] = coef * __expf(qc * d1 * d1);
      pr[2] = coef * __expf(qc * d2 * d2);
      pr[3] = coef * __expf(qc * d3 * d3);
      *reinterpret_cast<f32x4*>(pp + c0) = pr;
      *reinterpret_cast<f32x4*>(tp + c0) = stv;
    }
    return;
  }

  // ---------------- attention: V + series ----------------
  const int bid = blockIdx.x;
  const int wv = tid >> 6, ln = tid & 63;
  const int g = ln >> 4, n16 = ln & 15;
  const int bh = bid & 31, b = bh >> 3, h = bh & 7;
  const int qt = 31 - (bid >> 5);              // heaviest tiles dispatched first
  const int qb = qt * 32;
  const int nch = (qt >> 1) + 1;               // 64-s chunks covering causal extent
  const int qw = qb + wv * 16;                 // wave's q base
  const int qlane = qw + n16;                  // this lane's softmax row

  const float* Qp = Qg + ((size_t)(b * 1024) * 8 + h) * 64;
  const float* Kp = Kg + ((size_t)(b * 1024) * 8 + h) * 64;
  const float* Vp = Vg + ((size_t)(b * 1024) * 8 + h) * 64;

  // Q fragments (B-operand of swapped QK^T): lane holds Q[q=n16][8g..8g+7] (+32)
  const float* qrow = Qp + (size_t)(qw + n16) * 512 + 8 * g;
  const bf16x8 qf0 = pack_bf8(*(const f32x4*)(qrow),      *(const f32x4*)(qrow + 4));
  const bf16x8 qf1 = pack_bf8(*(const f32x4*)(qrow + 32), *(const f32x4*)(qrow + 36));

  f32x4 O[4] = {};                             // O[dt]: rows q=4g+r, col d=dt*16+n16
  float m = -1e30f, lsum = 0.f;

  const int spair = tid & 31, dgrp = tid >> 5; // V staging map (128 thr)
  unsigned short* Plw = Pl + wv * (16 * 72);

  for (int c = 0; c < nch; ++c) {
    __syncthreads();                           // Vt free (prev PV done)

    // issue V loads early (latency hides under QK^T)
    f32x4 vreg[8];
    const float* vb0 = Vp + (size_t)(c * 64 + 2 * spair) * 512 + dgrp * 16;
#pragma unroll
    for (int j = 0; j < 4; ++j) {
      vreg[2 * j]     = *(const f32x4*)(vb0 + 4 * j);
      vreg[2 * j + 1] = *(const f32x4*)(vb0 + 512 + 4 * j);
    }

    // QK^T: 4 16-s tiles; A=K (row s), B=Q^T (col q) -> D = S^T
    float x[4][4];
#pragma unroll
    for (int t = 0; t < 4; ++t) {
      const int sb = c * 64 + t * 16;
      const float* krow = Kp + (size_t)(sb + n16) * 512 + 8 * g;
      const bf16x8 kf0 = pack_bf8(*(const f32x4*)(krow),      *(const f32x4*)(krow + 4));
      const bf16x8 kf1 = pack_bf8(*(const f32x4*)(krow + 32), *(const f32x4*)(krow + 36));
      f32x4 acc = {0.f, 0.f, 0.f, 0.f};
      acc = __builtin_amdgcn_mfma_f32_16x16x32_bf16(kf0, qf0, acc, 0, 0, 0);
      acc = __builtin_amdgcn_mfma_f32_16x16x32_bf16(kf1, qf1, acc, 0, 0, 0);
#pragma unroll
      for (int r = 0; r < 4; ++r) {
        const int s = sb + 4 * g + r;
        x[t][r] = (s <= qlane) ? acc[r] * 0.125f : -1e30f;
      }
    }

    // chunk row-max (row q=n16 lives in this lane's 16 vals x 4 g-lanes)
    float pm = x[0][0];
#pragma unroll
    for (int t = 0; t < 4; ++t)
#pragma unroll
      for (int r = 0; r < 4; ++r) pm = fmaxf(pm, x[t][r]);
    pm = fmaxf(pm, __shfl_xor(pm, 16));
    pm = fmaxf(pm, __shfl_xor(pm, 32));

    if (!__all(pm <= m)) {                     // exact skip when max didn't grow
      const float mn  = fmaxf(m, pm);
      const float fsc = __expf(m - mn);
      lsum *= fsc;
#pragma unroll
      for (int r = 0; r < 4; ++r) {
        const float fr = __shfl(fsc, 4 * g + r);   // lane 4g+r holds factor for row q=4g+r
#pragma unroll
        for (int dt = 0; dt < 4; ++dt) O[dt][r] *= fr;
      }
      m = mn;
    }

    // e = exp(x-m): write P (bf16) to per-wave LDS, accumulate l
    float csum = 0.f;
#pragma unroll
    for (int t = 0; t < 4; ++t) {
      const float e0 = __expf(x[t][0] - m), e1 = __expf(x[t][1] - m);
      const float e2 = __expf(x[t][2] - m), e3 = __expf(x[t][3] - m);
      csum += (e0 + e1) + (e2 + e3);
      u16x4 pk = {f2bf(e0), f2bf(e1), f2bf(e2), f2bf(e3)};
      *reinterpret_cast<u16x4*>(Plw + n16 * 72 + t * 16 + 4 * g) = pk;
    }
    csum += __shfl_xor(csum, 16);
    csum += __shfl_xor(csum, 32);
    lsum += csum;

    // stage V^T into LDS (bf16), conflict-free ushort2 writes
#pragma unroll
    for (int j = 0; j < 4; ++j)
#pragma unroll
      for (int i = 0; i < 4; ++i) {
        u16x2 w = {f2bf(vreg[2 * j][i]), f2bf(vreg[2 * j + 1][i])};
        *reinterpret_cast<u16x2*>(&Vt[(dgrp * 16 + 4 * j + i) * 72 + 2 * spair]) = w;
      }
    __syncthreads();

    // PV: A=P (row q), B=V (col d) -> accumulate O[q][d]
#pragma unroll
    for (int h2 = 0; h2 < 2; ++h2) {
      const bf16x8 pa = *reinterpret_cast<const bf16x8*>(Plw + n16 * 72 + h2 * 32 + 8 * g);
#pragma unroll
      for (int dt = 0; dt < 4; ++dt) {
        const bf16x8 vbf =
            *reinterpret_cast<const bf16x8*>(&Vt[(dt * 16 + n16) * 72 + h2 * 32 + 8 * g]);
        O[dt] = __builtin_amdgcn_mfma_f32_16x16x32_bf16(pa, vbf, O[dt], 0, 0, 0);
      }
    }
  }

  // finalize V output
  const float invl = 1.f / lsum;               // for q=n16
  float invT[4];
#pragma unroll
  for (int r = 0; r < 4; ++r) invT[r] = __shfl(invl, 4 * g + r);
  float* Vo = outV + ((size_t)(b * 1024) * 8 + h) * 64;
#pragma unroll
  for (int dt = 0; dt < 4; ++dt)
#pragma unroll
    for (int r = 0; r < 4; ++r)
      Vo[(size_t)(qw + 4 * g + r) * 512 + dt * 16 + n16] = O[dt][r] * invT[r];

  // pass 2: recompute QK^T, emit series with final m,l (float4 stores)
  float* Srow = outS + (((size_t)bh * 1024 + qlane) << 10);
  for (int c = 0; c < 16; ++c) {
    if (c < nch) {
#pragma unroll
      for (int t = 0; t < 4; ++t) {
        const int sb = c * 64 + t * 16;
        const float* krow = Kp + (size_t)(sb + n16) * 512 + 8 * g;
        const bf16x8 kf0 = pack_bf8(*(const f32x4*)(krow),      *(const f32x4*)(krow + 4));
        const bf16x8 kf1 = pack_bf8(*(const f32x4*)(krow + 32), *(const f32x4*)(krow + 36));
        f32x4 acc = {0.f, 0.f, 0.f, 0.f};
        acc = __builtin_amdgcn_mfma_f32_16x16x32_bf16(kf0, qf0, acc, 0, 0, 0);
        acc = __builtin_amdgcn_mfma_f32_16x16x32_bf16(kf1, qf1, acc, 0, 0, 0);
        f32x4 ev;
#pragma unroll
        for (int r = 0; r < 4; ++r) {
          const int s = sb + 4 * g + r;
          ev[r] = (s <= qlane) ? __expf(acc[r] * 0.125f - m) * invl : 0.f;
        }
        *reinterpret_cast<f32x4*>(Srow + sb + 4 * g) = ev;
      }
    } else {
      const f32x4 z = {0.f, 0.f, 0.f, 0.f};
#pragma unroll
      for (int t = 0; t < 4; ++t)
        *reinterpret_cast<f32x4*>(Srow + c * 64 + t * 16 + 4 * g) = z;
    }
  }
}

}  // namespace

extern "C" void kernel_launch(void* const* d_in, const int* in_sizes, int n_in,
                              void* d_out, int out_size, void* d_ws, size_t ws_size,
                              hipStream_t stream) {
  const float* Qg   = (const float*)d_in[0];
  const float* Kg   = (const float*)d_in[1];
  const float* Vg   = (const float*)d_in[2];
  const float* Sg   = (const float*)d_in[3];
  const float* sacg = (const float*)d_in[4];
  const int*   tg   = (const int*)d_in[5];

  float* out  = (float*)d_out;
  float* outV = out;                       // [B,L,H,D]  = 2097152
  float* outS = out + (size_t)2097152;     // [B,H,L,S]  = 33554432
  float* outP = out + (size_t)35651584;    // prior
  float* outT = out + (size_t)69206016;    // sigma_t

  hipLaunchKernelGGL(fused_all, dim3(ATT_BLOCKS + PRIOR_BLOCKS), dim3(128), 0, stream,
                     Qg, Kg, Vg, Sg, sacg, tg, outV, outS, outP, outT);
}

// Round 3
// 107.115 us; speedup vs baseline: 4.8989x; 1.3572x over previous
//
#include <hip/hip_runtime.h>
#include <hip/hip_bf16.h>
#include <cstddef>
#include <cstdint>

namespace {

using f32x4  = __attribute__((ext_vector_type(4))) float;
using bf16x8 = __attribute__((ext_vector_type(8))) short;
using u16x2  = __attribute__((ext_vector_type(2))) unsigned short;
using u16x4  = __attribute__((ext_vector_type(4))) unsigned short;

constexpr int ATT_BLOCKS   = 1024;  // 32 qtiles(32 rows) x 32 (b,h); heavy qtiles first
constexpr int PRIOR_BLOCKS = 8192;  // 4 rows each -> 32768 rows
constexpr int PSTR = 1032;          // P LDS row stride (shorts): 2064 B -> 4-bank row shift

__device__ inline unsigned short f2bf(float x) {
  __hip_bfloat16 hv = __float2bfloat16(x);
  return *reinterpret_cast<unsigned short*>(&hv);
}
__device__ inline float bf2f(unsigned short u) {
  return __uint_as_float(((unsigned int)u) << 16);
}
__device__ inline bf16x8 pack_bf8(f32x4 a, f32x4 b) {
  bf16x8 r;
  r[0] = (short)f2bf(a[0]); r[1] = (short)f2bf(a[1]);
  r[2] = (short)f2bf(a[2]); r[3] = (short)f2bf(a[3]);
  r[4] = (short)f2bf(b[0]); r[5] = (short)f2bf(b[1]);
  r[6] = (short)f2bf(b[2]); r[7] = (short)f2bf(b[3]);
  return r;
}

__global__ __launch_bounds__(256) void fused_all(
    const float* __restrict__ Qg, const float* __restrict__ Kg,
    const float* __restrict__ Vg, const float* __restrict__ Sg,
    const float* __restrict__ sacg, const int* __restrict__ tg,
    float* __restrict__ outV, float* __restrict__ outS,
    float* __restrict__ outP, float* __restrict__ outT)
{
  __shared__ unsigned short Pl[32 * PSTR];   // unnormalized exp(scores), bf16: [q_local][s]
  __shared__ unsigned short Vt[64 * 72];     // V^T bf16: [d][s], stride 72
  __shared__ float red[4][32];
  __shared__ float invl[32];

  const int tid = threadIdx.x;

  if (blockIdx.x >= ATT_BLOCKS) {
    // ---------------- prior + sigma_t (pure streaming) ----------------
    const int pb = blockIdx.x - ATT_BLOCKS;
    const int r0 = pb * 4 + (tid >> 6);      // global row in [B][H][L]
    const int ln = tid & 63;
    const int b  = r0 >> 13;
    const int hh = (r0 >> 10) & 7;
    const int l  = r0 & 1023;
    const float sgv = Sg[(size_t)(b * 1024 + l) * 8 + hh];
    const float sac = sacg[tg[b]];
    const float sig = 1.f / (1.f + __expf(-5.f * sgv)) + 1e-5f;
    const float st  = sac * expm1f(sig * 1.0986122886681098f);  // sac*(3^sig-1)
    const float coef = 0.3989422804014327f / st;
    const float qc   = -0.5f / (st * st);
    float* pp = outP + ((size_t)r0 << 10);
    float* tp = outT + ((size_t)r0 << 10);
    const f32x4 stv = {st, st, st, st};
#pragma unroll
    for (int j = 0; j < 4; ++j) {
      const int c0 = j * 256 + ln * 4;
      const float d0 = (float)(l - c0);
      const float d1 = d0 - 1.f, d2 = d0 - 2.f, d3 = d0 - 3.f;
      f32x4 pr;
      pr[0] = coef * __expf(qc * d0 * d0);
      pr[1] = coef * __expf(qc * d1 * d1);
      pr[2] = coef * __expf(qc * d2 * d2);
      pr[3] = coef * __expf(qc * d3 * d3);
      *reinterpret_cast<f32x4*>(pp + c0) = pr;
      *reinterpret_cast<f32x4*>(tp + c0) = stv;
    }
    return;
  }

  // ---------------- attention: V + series, single pass ----------------
  const int bid = blockIdx.x;
  const int w = tid >> 6, ln = tid & 63;
  const int g = ln >> 4, n16 = ln & 15;
  const int bh = bid & 31, b = bh >> 3, h = bh & 7;
  const int qt = 31 - (bid >> 5);            // heavy tiles dispatched first
  const int qb = qt * 32;
  const int nch = (qt >> 1) + 1;             // 64-s chunks covering causal extent

  const float* Qbase = Qg + ((size_t)(b * 1024) * 8 + h) * 64;
  const float* Kbase = Kg + ((size_t)(b * 1024) * 8 + h) * 64;
  const float* Vbase = Vg + ((size_t)(b * 1024) * 8 + h) * 64;

  // Q B-fragments: lane holds Q[q = u*16 + n16][8g..8g+7] for each 32-k half
  bf16x8 qf[2][2];
#pragma unroll
  for (int u = 0; u < 2; ++u) {
    const float* qr = Qbase + (size_t)(qb + u * 16 + n16) * 512 + 8 * g;
    qf[u][0] = pack_bf8(*(const f32x4*)(qr),      *(const f32x4*)(qr + 4));
    qf[u][1] = pack_bf8(*(const f32x4*)(qr + 32), *(const f32x4*)(qr + 36));
  }

  f32x4 O[2] = {};                           // wave owns d-subtile w; O[u] = q-subtile u
  float cs[2] = {0.f, 0.f};

  const int spair = tid & 31, dgrp = tid >> 5;  // V staging map

  for (int c = 0; c < nch; ++c) {
    // K A-fragments for this wave's s-subtile (rows c*64 + w*16 + n16)
    const float* kr = Kbase + (size_t)(c * 64 + w * 16 + n16) * 512 + 8 * g;
    const bf16x8 kf0 = pack_bf8(*(const f32x4*)(kr),      *(const f32x4*)(kr + 4));
    const bf16x8 kf1 = pack_bf8(*(const f32x4*)(kr + 32), *(const f32x4*)(kr + 36));

    // V loads (2 rows x 8 cols per thread), issued early
    const float* vb = Vbase + (size_t)(c * 64 + 2 * spair) * 512 + dgrp * 8;
    const f32x4 va0 = *(const f32x4*)(vb);
    const f32x4 va1 = *(const f32x4*)(vb + 4);
    const f32x4 vc0 = *(const f32x4*)(vb + 512);
    const f32x4 vc1 = *(const f32x4*)(vb + 516);

    __syncthreads();                         // prev chunk's PV done reading Vt

    // stage V^T (bf16) into Vt[d][s]
#pragma unroll
    for (int i = 0; i < 4; ++i) {
      u16x2 w0 = {f2bf(va0[i]), f2bf(vc0[i])};
      *reinterpret_cast<u16x2*>(&Vt[(dgrp * 8 + i) * 72 + 2 * spair]) = w0;
      u16x2 w1 = {f2bf(va1[i]), f2bf(vc1[i])};
      *reinterpret_cast<u16x2*>(&Vt[(dgrp * 8 + 4 + i) * 72 + 2 * spair]) = w1;
    }

    // QK^T (swapped: A=K rows s, B=Q cols q) -> exp (m=0) -> P LDS
#pragma unroll
    for (int u = 0; u < 2; ++u) {
      f32x4 acc = {0.f, 0.f, 0.f, 0.f};
      acc = __builtin_amdgcn_mfma_f32_16x16x32_bf16(kf0, qf[u][0], acc, 0, 0, 0);
      acc = __builtin_amdgcn_mfma_f32_16x16x32_bf16(kf1, qf[u][1], acc, 0, 0, 0);
      const int qlane = qb + u * 16 + n16;
      const int sbase = c * 64 + w * 16 + 4 * g;
      const float e0 = (sbase + 0 <= qlane) ? __expf(acc[0] * 0.125f) : 0.f;
      const float e1 = (sbase + 1 <= qlane) ? __expf(acc[1] * 0.125f) : 0.f;
      const float e2 = (sbase + 2 <= qlane) ? __expf(acc[2] * 0.125f) : 0.f;
      const float e3 = (sbase + 3 <= qlane) ? __expf(acc[3] * 0.125f) : 0.f;
      cs[u] += (e0 + e1) + (e2 + e3);
      u16x4 pk = {f2bf(e0), f2bf(e1), f2bf(e2), f2bf(e3)};
      *reinterpret_cast<u16x4*>(&Pl[(u * 16 + n16) * PSTR + sbase]) = pk;
    }

    __syncthreads();                         // P + Vt ready

    // PV: A = P rows q (from Pl), B = V cols d (from Vt); wave's d-subtile = w
#pragma unroll
    for (int u = 0; u < 2; ++u)
#pragma unroll
      for (int h2 = 0; h2 < 2; ++h2) {
        const bf16x8 pa =
            *reinterpret_cast<const bf16x8*>(&Pl[(u * 16 + n16) * PSTR + c * 64 + h2 * 32 + 8 * g]);
        const bf16x8 vv =
            *reinterpret_cast<const bf16x8*>(&Vt[(w * 16 + n16) * 72 + h2 * 32 + 8 * g]);
        O[u] = __builtin_amdgcn_mfma_f32_16x16x32_bf16(pa, vv, O[u], 0, 0, 0);
      }
  }

  // row sums -> invl
  cs[0] += __shfl_xor(cs[0], 16); cs[0] += __shfl_xor(cs[0], 32);
  cs[1] += __shfl_xor(cs[1], 16); cs[1] += __shfl_xor(cs[1], 32);
  if (ln < 16) { red[w][n16] = cs[0]; red[w][16 + n16] = cs[1]; }
  __syncthreads();
  if (tid < 32) {
    const float s = red[0][tid] + red[1][tid] + red[2][tid] + red[3][tid];
    invl[tid] = 1.f / s;
  }
  __syncthreads();

  // V output: rows q = qb + u*16 + 4g + r, col d = w*16 + n16
  {
    float* Vo = outV + ((size_t)(b * 1024) * 8 + h) * 64;
#pragma unroll
    for (int u = 0; u < 2; ++u)
#pragma unroll
      for (int r = 0; r < 4; ++r) {
        const int qrow = u * 16 + 4 * g + r;
        Vo[(size_t)(qb + qrow) * 512 + w * 16 + n16] = O[u][r] * invl[qrow];
      }
  }

  // series output: coalesced f32x4 rows from Pl * invl
  {
    const int r = tid >> 3, sub = tid & 7;
    float* Srow = outS + ((size_t)bh * 1024 + qb + r) * 1024;
    const float il = invl[r];
    const int slim = nch * 64;
#pragma unroll 4
    for (int j = 0; j < 32; ++j) {
      const int s = j * 32 + sub * 4;
      f32x4 o;
      if (s < slim) {
        const u16x4 p = *reinterpret_cast<const u16x4*>(&Pl[r * PSTR + s]);
        o[0] = bf2f(p[0]) * il;
        o[1] = bf2f(p[1]) * il;
        o[2] = bf2f(p[2]) * il;
        o[3] = bf2f(p[3]) * il;
      } else {
        o = (f32x4){0.f, 0.f, 0.f, 0.f};
      }
      *reinterpret_cast<f32x4*>(Srow + s) = o;
    }
  }
}

}  // namespace

extern "C" void kernel_launch(void* const* d_in, const int* in_sizes, int n_in,
                              void* d_out, int out_size, void* d_ws, size_t ws_size,
                              hipStream_t stream) {
  const float* Qg   = (const float*)d_in[0];
  const float* Kg   = (const float*)d_in[1];
  const float* Vg   = (const float*)d_in[2];
  const float* Sg   = (const float*)d_in[3];
  const float* sacg = (const float*)d_in[4];
  const int*   tg   = (const int*)d_in[5];

  float* out  = (float*)d_out;
  float* outV = out;                       // [B,L,H,D]  = 2097152
  float* outS = out + (size_t)2097152;     // [B,H,L,S]  = 33554432
  float* outP = out + (size_t)35651584;    // prior
  float* outT = out + (size_t)69206016;    // sigma_t

  hipLaunchKernelGGL(fused_all, dim3(ATT_BLOCKS + PRIOR_BLOCKS), dim3(256), 0, stream,
                     Qg, Kg, Vg, Sg, sacg, tg, outV, outS, outP, outT);
}

// Round 4
// 82.502 us; speedup vs baseline: 6.3605x; 1.2983x over previous
//
#include <hip/hip_runtime.h>
#include <hip/hip_bf16.h>
#include <cstddef>
#include <cstdint>

namespace {

using f32x4  = __attribute__((ext_vector_type(4))) float;
using bf16x8 = __attribute__((ext_vector_type(8))) short;
using u16x2  = __attribute__((ext_vector_type(2))) unsigned short;
using u16x4  = __attribute__((ext_vector_type(4))) unsigned short;

constexpr int TOTAL_BLOCKS = 9216;  // 1024 attn (bid%9==0) + 8192 prior
constexpr int PSTR = 1032;          // P LDS row stride (shorts): 2064 B -> 4-bank row shift

__device__ inline unsigned short f2bf(float x) {
  __hip_bfloat16 hv = __float2bfloat16(x);
  return *reinterpret_cast<unsigned short*>(&hv);
}
__device__ inline float bf2f(unsigned short u) {
  return __uint_as_float(((unsigned int)u) << 16);
}
__device__ inline bf16x8 pack_bf8(f32x4 a, f32x4 b) {
  bf16x8 r;
  r[0] = (short)f2bf(a[0]); r[1] = (short)f2bf(a[1]);
  r[2] = (short)f2bf(a[2]); r[3] = (short)f2bf(a[3]);
  r[4] = (short)f2bf(b[0]); r[5] = (short)f2bf(b[1]);
  r[6] = (short)f2bf(b[2]); r[7] = (short)f2bf(b[3]);
  return r;
}

__global__ __launch_bounds__(256) void fused_all(
    const float* __restrict__ Qg, const float* __restrict__ Kg,
    const float* __restrict__ Vg, const float* __restrict__ Sg,
    const float* __restrict__ sacg, const int* __restrict__ tg,
    float* __restrict__ outV, float* __restrict__ outS,
    float* __restrict__ outP, float* __restrict__ outT)
{
  __shared__ unsigned short Pl[32 * PSTR];   // unnormalized exp(scores), bf16: [q_local][s]
  __shared__ unsigned short Vt[64 * 72];     // V^T bf16: [d][s], stride 72
  __shared__ float red[4][32];
  __shared__ float invl[32];

  const int tid = threadIdx.x;
  const int bid = blockIdx.x;
  const int role9 = bid / 9;

  if (bid - role9 * 9 != 0) {
    // ---------------- prior + sigma_t (pure streaming, interleaved) ----------------
    const int pb = role9 * 8 + (bid - role9 * 9) - 1;   // 0..8191
    const int r0 = pb * 4 + (tid >> 6);      // global row in [B][H][L]
    const int ln = tid & 63;
    const int b  = r0 >> 13;
    const int hh = (r0 >> 10) & 7;
    const int l  = r0 & 1023;
    const float sgv = Sg[(size_t)(b * 1024 + l) * 8 + hh];
    const float sac = sacg[tg[b]];
    const float sig = 1.f / (1.f + __expf(-5.f * sgv)) + 1e-5f;
    const float st  = sac * expm1f(sig * 1.0986122886681098f);  // sac*(3^sig-1)
    const float coef = 0.3989422804014327f / st;
    const float qc   = -0.5f / (st * st);
    float* pp = outP + ((size_t)r0 << 10);
    float* tp = outT + ((size_t)r0 << 10);
    const f32x4 stv = {st, st, st, st};
#pragma unroll
    for (int j = 0; j < 4; ++j) {
      const int c0 = j * 256 + ln * 4;
      const float d0 = (float)(l - c0);
      const float d1 = d0 - 1.f, d2 = d0 - 2.f, d3 = d0 - 3.f;
      f32x4 pr;
      pr[0] = coef * __expf(qc * d0 * d0);
      pr[1] = coef * __expf(qc * d1 * d1);
      pr[2] = coef * __expf(qc * d2 * d2);
      pr[3] = coef * __expf(qc * d3 * d3);
      __builtin_nontemporal_store(pr, reinterpret_cast<f32x4*>(pp + c0));
      __builtin_nontemporal_store(stv, reinterpret_cast<f32x4*>(tp + c0));
    }
    return;
  }

  // ---------------- attention: V + series, single pass ----------------
  const int aid = role9;                     // 0..1023
  const int w = tid >> 6, ln = tid & 63;
  const int g = ln >> 4, n16 = ln & 15;
  const int bh = aid & 31, b = bh >> 3, h = bh & 7;
  const int qt = 31 - (aid >> 5);            // heavy tiles dispatched first
  const int qb = qt * 32;
  const int nch = (qt >> 1) + 1;             // 64-s chunks covering causal extent

  const float* Qbase = Qg + ((size_t)(b * 1024) * 8 + h) * 64;
  const float* Kbase = Kg + ((size_t)(b * 1024) * 8 + h) * 64;
  const float* Vbase = Vg + ((size_t)(b * 1024) * 8 + h) * 64;

  // Q B-fragments: lane holds Q[q = u*16 + n16][8g..8g+7] for each 32-k half
  bf16x8 qf[2][2];
#pragma unroll
  for (int u = 0; u < 2; ++u) {
    const float* qr = Qbase + (size_t)(qb + u * 16 + n16) * 512 + 8 * g;
    qf[u][0] = pack_bf8(*(const f32x4*)(qr),      *(const f32x4*)(qr + 4));
    qf[u][1] = pack_bf8(*(const f32x4*)(qr + 32), *(const f32x4*)(qr + 36));
  }

  f32x4 O[2] = {};                           // wave owns d-subtile w; O[u] = q-subtile u
  float cs[2] = {0.f, 0.f};

  const int spair = tid & 31, dgrp = tid >> 5;  // V staging map

  for (int c = 0; c < nch; ++c) {
    // K A-fragments for this wave's s-subtile (rows c*64 + w*16 + n16)
    const float* kr = Kbase + (size_t)(c * 64 + w * 16 + n16) * 512 + 8 * g;
    const bf16x8 kf0 = pack_bf8(*(const f32x4*)(kr),      *(const f32x4*)(kr + 4));
    const bf16x8 kf1 = pack_bf8(*(const f32x4*)(kr + 32), *(const f32x4*)(kr + 36));

    // V loads (2 rows x 8 cols per thread), issued early
    const float* vb = Vbase + (size_t)(c * 64 + 2 * spair) * 512 + dgrp * 8;
    const f32x4 va0 = *(const f32x4*)(vb);
    const f32x4 va1 = *(const f32x4*)(vb + 4);
    const f32x4 vc0 = *(const f32x4*)(vb + 512);
    const f32x4 vc1 = *(const f32x4*)(vb + 516);

    __syncthreads();                         // prev chunk's PV done reading Vt

    // stage V^T (bf16) into Vt[d][s]
#pragma unroll
    for (int i = 0; i < 4; ++i) {
      u16x2 w0 = {f2bf(va0[i]), f2bf(vc0[i])};
      *reinterpret_cast<u16x2*>(&Vt[(dgrp * 8 + i) * 72 + 2 * spair]) = w0;
      u16x2 w1 = {f2bf(va1[i]), f2bf(vc1[i])};
      *reinterpret_cast<u16x2*>(&Vt[(dgrp * 8 + 4 + i) * 72 + 2 * spair]) = w1;
    }

    // QK^T (swapped: A=K rows s, B=Q cols q) -> exp (m=0) -> P LDS
#pragma unroll
    for (int u = 0; u < 2; ++u) {
      f32x4 acc = {0.f, 0.f, 0.f, 0.f};
      acc = __builtin_amdgcn_mfma_f32_16x16x32_bf16(kf0, qf[u][0], acc, 0, 0, 0);
      acc = __builtin_amdgcn_mfma_f32_16x16x32_bf16(kf1, qf[u][1], acc, 0, 0, 0);
      const int qlane = qb + u * 16 + n16;
      const int sbase = c * 64 + w * 16 + 4 * g;
      const float e0 = (sbase + 0 <= qlane) ? __expf(acc[0] * 0.125f) : 0.f;
      const float e1 = (sbase + 1 <= qlane) ? __expf(acc[1] * 0.125f) : 0.f;
      const float e2 = (sbase + 2 <= qlane) ? __expf(acc[2] * 0.125f) : 0.f;
      const float e3 = (sbase + 3 <= qlane) ? __expf(acc[3] * 0.125f) : 0.f;
      cs[u] += (e0 + e1) + (e2 + e3);
      u16x4 pk = {f2bf(e0), f2bf(e1), f2bf(e2), f2bf(e3)};
      *reinterpret_cast<u16x4*>(&Pl[(u * 16 + n16) * PSTR + sbase]) = pk;
    }

    __syncthreads();                         // P + Vt ready

    // PV: A = P rows q (from Pl), B = V cols d (from Vt); wave's d-subtile = w
#pragma unroll
    for (int u = 0; u < 2; ++u)
#pragma unroll
      for (int h2 = 0; h2 < 2; ++h2) {
        const bf16x8 pa =
            *reinterpret_cast<const bf16x8*>(&Pl[(u * 16 + n16) * PSTR + c * 64 + h2 * 32 + 8 * g]);
        const bf16x8 vv =
            *reinterpret_cast<const bf16x8*>(&Vt[(w * 16 + n16) * 72 + h2 * 32 + 8 * g]);
        O[u] = __builtin_amdgcn_mfma_f32_16x16x32_bf16(pa, vv, O[u], 0, 0, 0);
      }
  }

  // row sums -> invl
  cs[0] += __shfl_xor(cs[0], 16); cs[0] += __shfl_xor(cs[0], 32);
  cs[1] += __shfl_xor(cs[1], 16); cs[1] += __shfl_xor(cs[1], 32);
  if (ln < 16) { red[w][n16] = cs[0]; red[w][16 + n16] = cs[1]; }
  __syncthreads();
  if (tid < 32) {
    const float s = red[0][tid] + red[1][tid] + red[2][tid] + red[3][tid];
    invl[tid] = 1.f / s;
  }
  __syncthreads();

  // V output: rows q = qb + u*16 + 4g + r, col d = w*16 + n16
  {
    float* Vo = outV + ((size_t)(b * 1024) * 8 + h) * 64;
#pragma unroll
    for (int u = 0; u < 2; ++u)
#pragma unroll
      for (int r = 0; r < 4; ++r) {
        const int qrow = u * 16 + 4 * g + r;
        __builtin_nontemporal_store(O[u][r] * invl[qrow],
                                    Vo + (size_t)(qb + qrow) * 512 + w * 16 + n16);
      }
  }

  // series output: coalesced f32x4 rows from Pl * invl
  {
    const int r = tid >> 3, sub = tid & 7;
    float* Srow = outS + ((size_t)bh * 1024 + qb + r) * 1024;
    const float il = invl[r];
    const int slim = nch * 64;
#pragma unroll 4
    for (int j = 0; j < 32; ++j) {
      const int s = j * 32 + sub * 4;
      f32x4 o;
      if (s < slim) {
        const u16x4 p = *reinterpret_cast<const u16x4*>(&Pl[r * PSTR + s]);
        o[0] = bf2f(p[0]) * il;
        o[1] = bf2f(p[1]) * il;
        o[2] = bf2f(p[2]) * il;
        o[3] = bf2f(p[3]) * il;
      } else {
        o = (f32x4){0.f, 0.f, 0.f, 0.f};
      }
      __builtin_nontemporal_store(o, reinterpret_cast<f32x4*>(Srow + s));
    }
  }
}

}  // namespace

extern "C" void kernel_launch(void* const* d_in, const int* in_sizes, int n_in,
                              void* d_out, int out_size, void* d_ws, size_t ws_size,
                              hipStream_t stream) {
  const float* Qg   = (const float*)d_in[0];
  const float* Kg   = (const float*)d_in[1];
  const float* Vg   = (const float*)d_in[2];
  const float* Sg   = (const float*)d_in[3];
  const float* sacg = (const float*)d_in[4];
  const int*   tg   = (const int*)d_in[5];

  float* out  = (float*)d_out;
  float* outV = out;                       // [B,L,H,D]  = 2097152
  float* outS = out + (size_t)2097152;     // [B,H,L,S]  = 33554432
  float* outP = out + (size_t)35651584;    // prior
  float* outT = out + (size_t)69206016;    // sigma_t

  hipLaunchKernelGGL(fused_all, dim3(TOTAL_BLOCKS), dim3(256), 0, stream,
                     Qg, Kg, Vg, Sg, sacg, tg, outV, outS, outP, outT);
}

// Round 5
// 81.457 us; speedup vs baseline: 6.4420x; 1.0128x over previous
//
#include <hip/hip_runtime.h>
#include <hip/hip_bf16.h>
#include <cstddef>
#include <cstdint>

namespace {

using f32x4  = __attribute__((ext_vector_type(4))) float;
using bf16x8 = __attribute__((ext_vector_type(8))) short;
using u16x4  = __attribute__((ext_vector_type(4))) unsigned short;

constexpr int TOTAL_BLOCKS = 9216;  // 1024 attn (bid%9==0) + 8192 prior
constexpr int PSTR = 1032;          // P LDS row stride (shorts); 2064B rows, 16B-aligned

__device__ inline unsigned short f2bf(float x) {
  __hip_bfloat16 hv = __float2bfloat16(x);
  return *reinterpret_cast<unsigned short*>(&hv);
}
__device__ inline float bf2f(unsigned short u) {
  return __uint_as_float(((unsigned int)u) << 16);
}
__device__ inline bf16x8 pack_bf8(f32x4 a, f32x4 b) {
  bf16x8 r;
  r[0] = (short)f2bf(a[0]); r[1] = (short)f2bf(a[1]);
  r[2] = (short)f2bf(a[2]); r[3] = (short)f2bf(a[3]);
  r[4] = (short)f2bf(b[0]); r[5] = (short)f2bf(b[1]);
  r[6] = (short)f2bf(b[2]); r[7] = (short)f2bf(b[3]);
  return r;
}
__device__ inline bf16x8 pack8(const float* p) {
  bf16x8 r;
#pragma unroll
  for (int i = 0; i < 8; ++i) r[i] = (short)f2bf(p[i]);
  return r;
}

__global__ __launch_bounds__(256) void fused_all(
    const float* __restrict__ Qg, const float* __restrict__ Kg,
    const float* __restrict__ Vg, const float* __restrict__ Sg,
    const float* __restrict__ sacg, const int* __restrict__ tg,
    float* __restrict__ outV, float* __restrict__ outS,
    float* __restrict__ outP, float* __restrict__ outT)
{
  __shared__ unsigned short Pl[32 * PSTR];   // unnormalized exp(scores), bf16: [q_local][s]
  __shared__ float red[4][32];
  __shared__ float invl[32];

  const int tid = threadIdx.x;
  const int bid = blockIdx.x;
  const int role9 = bid / 9;

  if (bid - role9 * 9 != 0) {
    // ---------------- prior + sigma_t (pure streaming, interleaved) ----------------
    const int pb = role9 * 8 + (bid - role9 * 9) - 1;   // 0..8191
    const int r0 = pb * 4 + (tid >> 6);      // global row in [B][H][L]
    const int ln = tid & 63;
    const int b  = r0 >> 13;
    const int hh = (r0 >> 10) & 7;
    const int l  = r0 & 1023;
    const float sgv = Sg[(size_t)(b * 1024 + l) * 8 + hh];
    const float sac = sacg[tg[b]];
    const float sig = 1.f / (1.f + __expf(-5.f * sgv)) + 1e-5f;
    const float st  = sac * expm1f(sig * 1.0986122886681098f);  // sac*(3^sig-1)
    const float coef = 0.3989422804014327f / st;
    const float qc   = -0.5f / (st * st);
    float* pp = outP + ((size_t)r0 << 10);
    float* tp = outT + ((size_t)r0 << 10);
    const f32x4 stv = {st, st, st, st};
#pragma unroll
    for (int j = 0; j < 4; ++j) {
      const int c0 = j * 256 + ln * 4;
      const float d0 = (float)(l - c0);
      const float d1 = d0 - 1.f, d2 = d0 - 2.f, d3 = d0 - 3.f;
      f32x4 pr;
      pr[0] = coef * __expf(qc * d0 * d0);
      pr[1] = coef * __expf(qc * d1 * d1);
      pr[2] = coef * __expf(qc * d2 * d2);
      pr[3] = coef * __expf(qc * d3 * d3);
      __builtin_nontemporal_store(pr, reinterpret_cast<f32x4*>(pp + c0));
      __builtin_nontemporal_store(stv, reinterpret_cast<f32x4*>(tp + c0));
    }
    return;
  }

  // ---------------- attention: V + series, single pass, 1 barrier/chunk ----------------
  const int aid = role9;                     // 0..1023
  const int w = tid >> 6, ln = tid & 63;
  const int g = ln >> 4, n16 = ln & 15;
  const int bh = aid & 31, b = bh >> 3, h = bh & 7;
  const int qt = 31 - (aid >> 5);            // heavy tiles dispatched first
  const int qb = qt * 32;
  const int nch = (qt >> 1) + 1;             // 64-s chunks covering causal extent

  const float* Qbase = Qg + ((size_t)(b * 1024) * 8 + h) * 64;
  const float* Kbase = Kg + ((size_t)(b * 1024) * 8 + h) * 64;
  const float* Vbase = Vg + ((size_t)(b * 1024) * 8 + h) * 64;

  // Q B-fragments: lane holds Q[q = u*16 + n16][8g..8g+7] for each 32-k half
  bf16x8 qf[2][2];
#pragma unroll
  for (int u = 0; u < 2; ++u) {
    const float* qr = Qbase + (size_t)(qb + u * 16 + n16) * 512 + 8 * g;
    qf[u][0] = pack_bf8(*(const f32x4*)(qr),      *(const f32x4*)(qr + 4));
    qf[u][1] = pack_bf8(*(const f32x4*)(qr + 32), *(const f32x4*)(qr + 36));
  }

  f32x4 O[2] = {};                           // wave owns d-subtile w; O[u] = q-subtile u
  float cs[2] = {0.f, 0.f};

  // V columns for this wave's d-subtile: lane (g,n16) needs
  // V[s = c*64 + 32*h2 + 8*g + j][d = w*16 + n16], j = 0..7  (64B-coalesced per (h2,j))
  const float* vcol = Vbase + (size_t)(8 * g) * 512 + w * 16 + n16;

  float vrA[16], vrB[16];
  auto vload = [&](int c, float (&dst)[16]) {
    const float* p = vcol + (size_t)c * 64 * 512;
#pragma unroll
    for (int h2 = 0; h2 < 2; ++h2)
#pragma unroll
      for (int j = 0; j < 8; ++j)
        dst[h2 * 8 + j] = p[(size_t)(32 * h2 + j) * 512];
  };

  auto body = [&](int c, float (&vc)[16], float (&vn)[16]) {
    // K A-fragments for this wave's s-subtile (rows c*64 + w*16 + n16)
    const float* kr = Kbase + (size_t)(c * 64 + w * 16 + n16) * 512 + 8 * g;
    const bf16x8 kf0 = pack_bf8(*(const f32x4*)(kr),      *(const f32x4*)(kr + 4));
    const bf16x8 kf1 = pack_bf8(*(const f32x4*)(kr + 32), *(const f32x4*)(kr + 36));

    // QK^T (swapped: A=K rows s, B=Q cols q) -> exp (m=0) -> P LDS
#pragma unroll
    for (int u = 0; u < 2; ++u) {
      f32x4 acc = {0.f, 0.f, 0.f, 0.f};
      acc = __builtin_amdgcn_mfma_f32_16x16x32_bf16(kf0, qf[u][0], acc, 0, 0, 0);
      acc = __builtin_amdgcn_mfma_f32_16x16x32_bf16(kf1, qf[u][1], acc, 0, 0, 0);
      const int qlane = qb + u * 16 + n16;
      const int sbase = c * 64 + w * 16 + 4 * g;
      const float e0 = (sbase + 0 <= qlane) ? __expf(acc[0] * 0.125f) : 0.f;
      const float e1 = (sbase + 1 <= qlane) ? __expf(acc[1] * 0.125f) : 0.f;
      const float e2 = (sbase + 2 <= qlane) ? __expf(acc[2] * 0.125f) : 0.f;
      const float e3 = (sbase + 3 <= qlane) ? __expf(acc[3] * 0.125f) : 0.f;
      cs[u] += (e0 + e1) + (e2 + e3);
      u16x4 pk = {f2bf(e0), f2bf(e1), f2bf(e2), f2bf(e3)};
      *reinterpret_cast<u16x4*>(&Pl[(u * 16 + n16) * PSTR + sbase]) = pk;
    }

    if (c + 1 < nch) vload(c + 1, vn);       // prefetch next chunk's V columns

    __syncthreads();                         // P columns of chunk c visible

    // PV: A = P rows q (from Pl), B = V cols d (registers)
    const bf16x8 vv0 = pack8(&vc[0]);
    const bf16x8 vv1 = pack8(&vc[8]);
#pragma unroll
    for (int u = 0; u < 2; ++u) {
      const bf16x8 pa0 =
          *reinterpret_cast<const bf16x8*>(&Pl[(u * 16 + n16) * PSTR + c * 64 + 8 * g]);
      O[u] = __builtin_amdgcn_mfma_f32_16x16x32_bf16(pa0, vv0, O[u], 0, 0, 0);
      const bf16x8 pa1 =
          *reinterpret_cast<const bf16x8*>(&Pl[(u * 16 + n16) * PSTR + c * 64 + 32 + 8 * g]);
      O[u] = __builtin_amdgcn_mfma_f32_16x16x32_bf16(pa1, vv1, O[u], 0, 0, 0);
    }
  };

  vload(0, vrA);
  int c = 0;
  while (true) {
    body(c, vrA, vrB);
    if (++c >= nch) break;
    body(c, vrB, vrA);
    if (++c >= nch) break;
  }

  // row sums -> invl
  cs[0] += __shfl_xor(cs[0], 16); cs[0] += __shfl_xor(cs[0], 32);
  cs[1] += __shfl_xor(cs[1], 16); cs[1] += __shfl_xor(cs[1], 32);
  if (ln < 16) { red[w][n16] = cs[0]; red[w][16 + n16] = cs[1]; }
  __syncthreads();
  if (tid < 32) {
    const float s = red[0][tid] + red[1][tid] + red[2][tid] + red[3][tid];
    invl[tid] = 1.f / s;
  }
  __syncthreads();

  // V output: rows q = qb + u*16 + 4g + r, col d = w*16 + n16
  {
    float* Vo = outV + ((size_t)(b * 1024) * 8 + h) * 64;
#pragma unroll
    for (int u = 0; u < 2; ++u)
#pragma unroll
      for (int r = 0; r < 4; ++r) {
        const int qrow = u * 16 + 4 * g + r;
        __builtin_nontemporal_store(O[u][r] * invl[qrow],
                                    Vo + (size_t)(qb + qrow) * 512 + w * 16 + n16);
      }
  }

  // series output: coalesced f32x4 rows from Pl * invl
  {
    const int r = tid >> 3, sub = tid & 7;
    float* Srow = outS + ((size_t)bh * 1024 + qb + r) * 1024;
    const float il = invl[r];
    const int slim = nch * 64;
#pragma unroll 4
    for (int j = 0; j < 32; ++j) {
      const int s = j * 32 + sub * 4;
      f32x4 o;
      if (s < slim) {
        const u16x4 p = *reinterpret_cast<const u16x4*>(&Pl[r * PSTR + s]);
        o[0] = bf2f(p[0]) * il;
        o[1] = bf2f(p[1]) * il;
        o[2] = bf2f(p[2]) * il;
        o[3] = bf2f(p[3]) * il;
      } else {
        o = (f32x4){0.f, 0.f, 0.f, 0.f};
      }
      __builtin_nontemporal_store(o, reinterpret_cast<f32x4*>(Srow + s));
    }
  }
}

}  // namespace

extern "C" void kernel_launch(void* const* d_in, const int* in_sizes, int n_in,
                              void* d_out, int out_size, void* d_ws, size_t ws_size,
                              hipStream_t stream) {
  const float* Qg   = (const float*)d_in[0];
  const float* Kg   = (const float*)d_in[1];
  const float* Vg   = (const float*)d_in[2];
  const float* Sg   = (const float*)d_in[3];
  const float* sacg = (const float*)d_in[4];
  const int*   tg   = (const int*)d_in[5];

  float* out  = (float*)d_out;
  float* outV = out;                       // [B,L,H,D]  = 2097152
  float* outS = out + (size_t)2097152;     // [B,H,L,S]  = 33554432
  float* outP = out + (size_t)35651584;    // prior
  float* outT = out + (size_t)69206016;    // sigma_t

  hipLaunchKernelGGL(fused_all, dim3(TOTAL_BLOCKS), dim3(256), 0, stream,
                     Qg, Kg, Vg, Sg, sacg, tg, outV, outS, outP, outT);
}